// Round 10
// baseline (177.479 us; speedup 1.0000x reference)
//
#include <hip/hip_runtime.h>
#include <hip/hip_bf16.h>

#define NN 50000
#define NE 1600000
#define DD 128
#define NPB 64                 // nodes per bucket (dst>>6)
#define NBK 782                // ceil(NN/64)
#define MAXB 2560              // bucket slab capacity (mean 2048, +11 sigma)
#define CHUNK 3125             // NE / 512 exactly -> no straggler wave
#define NCB 512                // conv grid
#define MS 136                 // mean LDS tile stride (bf16): <=2-way banks

typedef __attribute__((ext_vector_type(8))) short short8;
typedef __attribute__((ext_vector_type(4))) float f32x4;

__device__ inline unsigned short to_bf16(float v) {
    __hip_bfloat16 h = __float2bfloat16(v);
    return __builtin_bit_cast(unsigned short, h);
}

// ---- phase 1: x->fp8, W/B->bf16 pack, bucket-sorted edge scatter --------
// 512 blocks x 512 thr, 3125 edges each (exact). Chunk counting-sorted by
// bucket in LDS; global ebuf writes lane-consecutive into bucket slabs.
__global__ __launch_bounds__(512) void convscatter_k(const int* __restrict__ ei,
                                                     const float* __restrict__ x,
                                                     const float* __restrict__ W,
                                                     const float* __restrict__ Bm,
                                                     unsigned int* __restrict__ xb,
                                                     unsigned int* __restrict__ Wb,
                                                     unsigned int* __restrict__ Bb,
                                                     int* __restrict__ gcursor,
                                                     int* __restrict__ ebuf) {
    __shared__ int stg[CHUNK];
    __shared__ int h[NBK];
    __shared__ int lbase[NBK];
    __shared__ int gb[NBK];
    __shared__ int hcur[NBK];
    __shared__ int wsum[8], wbase[8];
    const int t = threadIdx.x;
    const int lane = t & 63, wv = t >> 6;
    const int e0 = blockIdx.x * CHUNK;

    for (int i = t; i < NBK; i += 512) h[i] = 0;
    __syncthreads();

    unsigned int w2[7];
    #pragma unroll
    for (int u = 0; u < 7; ++u) {
        int i = u * 512 + t;
        if (i < CHUNK) {
            int src = ei[e0 + i];
            int dst = ei[NE + e0 + i];
            int b = dst >> 6;
            w2[u] = ((unsigned)b << 22) | ((unsigned)src << 6) | (unsigned)(dst & 63);
            atomicAdd(&h[b], 1);
        } else w2[u] = 0xFFFFFFFFu;
    }

    // independent global work: x -> fp8 ; W,B -> packed bf16
    {
        int gid = blockIdx.x * 512 + t;
        const int total4 = NN * DD / 4;  // 1.6M uints (4x fp8 each)
        for (int i = gid; i < total4; i += NCB * 512) {
            float4 v = ((const float4*)x)[i];
            int p = __builtin_amdgcn_cvt_pk_fp8_f32(v.x, v.y, 0, false);
            p = __builtin_amdgcn_cvt_pk_fp8_f32(v.z, v.w, p, true);
            xb[i] = (unsigned)p;
        }
        if (gid < 16384) {  // 2x 8192 uints (2 bf16 each)
            if (gid < 8192) {
                float2 w = ((const float2*)W)[gid];
                Wb[gid] = (unsigned)to_bf16(w.x) | ((unsigned)to_bf16(w.y) << 16);
            } else {
                float2 b = ((const float2*)Bm)[gid - 8192];
                Bb[gid - 8192] = (unsigned)to_bf16(b.x) | ((unsigned)to_bf16(b.y) << 16);
            }
        }
    }
    __syncthreads();

    // hierarchical scan (2 buckets/thread, 2 barriers)
    int b0 = 2 * t, b1 = b0 + 1;
    int h0 = (b0 < NBK) ? h[b0] : 0;
    int h1 = (b1 < NBK) ? h[b1] : 0;
    int v = h0 + h1, s = v;
    #pragma unroll
    for (int o = 1; o < 64; o <<= 1) {
        int u = __shfl_up(s, o);
        if (lane >= o) s += u;
    }
    if (lane == 63) wsum[wv] = s;
    __syncthreads();
    if (wv == 0 && lane < 8) {
        int bv = wsum[lane], bs = bv;
        #pragma unroll
        for (int o = 1; o < 8; o <<= 1) {
            int u = __shfl_up(bs, o);
            if (lane >= o) bs += u;
        }
        wbase[lane] = bs - bv;
    }
    __syncthreads();
    {
        int excl = s - v + wbase[wv];
        if (b0 < NBK) {
            lbase[b0] = excl; hcur[b0] = excl;
            gb[b0] = h0 ? b0 * MAXB + atomicAdd(&gcursor[b0], h0) : 0;
        }
        if (b1 < NBK) {
            lbase[b1] = excl + h0; hcur[b1] = excl + h0;
            gb[b1] = h1 ? b1 * MAXB + atomicAdd(&gcursor[b1], h1) : 0;
        }
    }
    __syncthreads();

    #pragma unroll
    for (int u = 0; u < 7; ++u) {
        if (w2[u] != 0xFFFFFFFFu) {
            int b = w2[u] >> 22;
            int pos = atomicAdd(&hcur[b], 1);
            stg[pos] = (int)w2[u];
        }
    }
    __syncthreads();

    for (int i = t; i < CHUNK; i += 512) {
        unsigned int w = (unsigned)stg[i];
        int b = w >> 22;
        ebuf[gb[b] + (i - lbase[b])] = (int)(w & 0x3FFFFFu);
    }
}

// ---- phase 2: fused per-bucket sort + aggregation + MFMA epilogue -------
// 512 thr = 8 waves per bucket. Sort edges by node -> srt; aggregate fp8
// gathers into registers; mean -> LDS bf16 tile; then MFMA epilogue for the
// same 64 rows: out = mean @ W^T + x @ B^T (x hi/lo split, W/B prepacked).
__global__ __launch_bounds__(512) void aggemm_k(const unsigned int* __restrict__ xb,
                                                const float* __restrict__ x,
                                                const unsigned short* __restrict__ Wb,
                                                const unsigned short* __restrict__ Bb,
                                                const int* __restrict__ ebuf,
                                                const int* __restrict__ gcursor,
                                                float* __restrict__ out) {
    __shared__ int stg[MAXB];
    __shared__ unsigned short srt[MAXB];
    __shared__ unsigned short meanT[NPB * MS];
    __shared__ int cnt8[8][NPB];
    __shared__ int cur[NPB], off[NPB + 1];
    const int b = blockIdx.x, t = threadIdx.x;
    const int wv = t >> 6, lane = t & 63;
    const int n = gcursor[b];
    const int* __restrict__ slab = ebuf + (size_t)b * MAXB;
    for (int i = t; i < n; i += 512) stg[i] = slab[i];
    if (lane < NPB) cnt8[wv][lane] = 0;
    __syncthreads();
    for (int i = t; i < n; i += 512) atomicAdd(&cnt8[wv][stg[i] & 63], 1);
    __syncthreads();
    if (t < 64) {
        int v = 0;
        #pragma unroll
        for (int w = 0; w < 8; ++w) v += cnt8[w][t];
        int s = v;
        #pragma unroll
        for (int o = 1; o < 64; o <<= 1) {
            int u = __shfl_up(s, o);
            if (t >= o) s += u;
        }
        cur[t] = s - v;
        off[t] = s - v;
        if (t == 63) off[64] = s;
    }
    __syncthreads();
    for (int i = t; i < n; i += 512) {
        int w = stg[i];
        int pos = atomicAdd(&cur[w & 63], 1);
        srt[pos] = (unsigned short)(w >> 6);
    }
    __syncthreads();

    // aggregation: wave wv handles nodes {wv + 8q}; half-wave = 1 edge row
    const int half = lane >> 5, il = lane & 31;
    #pragma unroll
    for (int q = 0; q < 8; ++q) {
        int ln = wv + q * 8;
        int s0 = off[ln], s1 = off[ln + 1];
        float a0 = 0.f, a1 = 0.f, a2 = 0.f, a3 = 0.f;
        int i = s0;
        for (; i + 16 <= s1; i += 16) {
            unsigned int u[8];
            #pragma unroll
            for (int k = 0; k < 8; ++k)
                u[k] = xb[(size_t)srt[i + 2 * k + half] * 32 + il];
            #pragma unroll
            for (int k = 0; k < 8; ++k) {
                auto lo = __builtin_amdgcn_cvt_pk_f32_fp8((int)u[k], false);
                auto hi = __builtin_amdgcn_cvt_pk_f32_fp8((int)u[k], true);
                a0 += lo[0]; a1 += lo[1]; a2 += hi[0]; a3 += hi[1];
            }
        }
        for (; i < s1; i += 2) {
            int e = i + half;
            unsigned int u = (e < s1) ? xb[(size_t)srt[e] * 32 + il] : 0u;
            auto lo = __builtin_amdgcn_cvt_pk_f32_fp8((int)u, false);
            auto hi = __builtin_amdgcn_cvt_pk_f32_fp8((int)u, true);
            a0 += lo[0]; a1 += lo[1]; a2 += hi[0]; a3 += hi[1];
        }
        a0 += __shfl_xor(a0, 32);
        a1 += __shfl_xor(a1, 32);
        a2 += __shfl_xor(a2, 32);
        a3 += __shfl_xor(a3, 32);
        if (half == 0) {
            float inv = 1.0f / fmaxf((float)(s1 - s0), 1.0f);
            ushort4 mp;
            mp.x = to_bf16(a0 * inv); mp.y = to_bf16(a1 * inv);
            mp.z = to_bf16(a2 * inv); mp.w = to_bf16(a3 * inv);
            *(ushort4*)&meanT[ln * MS + il * 4] = mp;
        }
    }
    __syncthreads();

    // MFMA epilogue: wave wv -> row-tile rt = wv>>1 (16 rows), n-half wv&1
    const int m = lane & 15, quad = lane >> 4;
    const int rt = wv >> 1, nh = wv & 1;
    const int bb = b * NPB;
    const int rowA = min(bb + rt * 16 + m, NN - 1);

    f32x4 acc[4];
    #pragma unroll
    for (int nt = 0; nt < 4; ++nt) acc[nt] = (f32x4){0.f, 0.f, 0.f, 0.f};

    #pragma unroll
    for (int kt = 0; kt < 4; ++kt) {
        const int k8 = kt * 32 + quad * 8;
        short8 mf = *(const short8*)&meanT[(rt * 16 + m) * MS + k8];
        float xv[8];
        {
            const float4* xq = (const float4*)&x[(size_t)rowA * DD + k8];
            float4 c0 = xq[0], c1 = xq[1];
            xv[0] = c0.x; xv[1] = c0.y; xv[2] = c0.z; xv[3] = c0.w;
            xv[4] = c1.x; xv[5] = c1.y; xv[6] = c1.z; xv[7] = c1.w;
        }
        short8 xh, xl;
        #pragma unroll
        for (int j = 0; j < 8; ++j) {
            unsigned short g = to_bf16(xv[j]);
            xh[j] = (short)g;
            xl[j] = (short)to_bf16(xv[j] - __uint_as_float((unsigned)g << 16));
        }
        #pragma unroll
        for (int nt = 0; nt < 4; ++nt) {
            int nrow = (nh * 4 + nt) * 16 + m;
            short8 wf = *(const short8*)&Wb[nrow * DD + k8];
            short8 bf = *(const short8*)&Bb[nrow * DD + k8];
            acc[nt] = __builtin_amdgcn_mfma_f32_16x16x32_bf16(xl, bf, acc[nt], 0, 0, 0);
            acc[nt] = __builtin_amdgcn_mfma_f32_16x16x32_bf16(mf, wf, acc[nt], 0, 0, 0);
            acc[nt] = __builtin_amdgcn_mfma_f32_16x16x32_bf16(xh, bf, acc[nt], 0, 0, 0);
        }
    }

    // C/D layout: col = lane&15, row = quad*4 + reg (verified m89/m91)
    const int rowD0 = bb + rt * 16 + quad * 4;
    #pragma unroll
    for (int nt = 0; nt < 4; ++nt) {
        #pragma unroll
        for (int r = 0; r < 4; ++r) {
            int row = rowD0 + r;
            if (row < NN) out[(size_t)row * DD + (nh * 4 + nt) * 16 + m] = acc[nt][r];
        }
    }
}

extern "C" void kernel_launch(void* const* d_in, const int* in_sizes, int n_in,
                              void* d_out, int out_size, void* d_ws, size_t ws_size,
                              hipStream_t stream) {
    const float* x  = (const float*)d_in[0];
    const int*   ei = (const int*)d_in[1];   // [2, NE] int32
    const float* W  = (const float*)d_in[2];
    const float* Bm = (const float*)d_in[3];
    float* out = (float*)d_out;

    unsigned int* xb = (unsigned int*)d_ws;             // NN*32 uints (fp8 quads)
    unsigned int* Wb = xb + (size_t)NN * 32;            // 8192 uints (bf16 pairs)
    unsigned int* Bb = Wb + 8192;                       // 8192 uints
    int* ebuf    = (int*)(Bb + 8192);                   // NBK*MAXB
    int* gcursor = ebuf + (size_t)NBK * MAXB;           // NBK

    hipMemsetAsync(gcursor, 0, NBK * sizeof(int), stream);
    convscatter_k<<<NCB, 512, 0, stream>>>(ei, x, W, Bm, xb, Wb, Bb, gcursor, ebuf);
    aggemm_k<<<NBK, 512, 0, stream>>>(xb, x, (const unsigned short*)Wb,
                                      (const unsigned short*)Bb, ebuf, gcursor, out);
}